// Round 10
// baseline (209.122 us; speedup 1.0000x reference)
//
#include <hip/hip_runtime.h>
#include <hip/hip_bf16.h>

typedef __attribute__((ext_vector_type(8))) short short8;
typedef __attribute__((ext_vector_type(4))) float f32x4;
typedef __attribute__((ext_vector_type(2))) unsigned int uint2v;
typedef unsigned int u32;

#define QSCALE 0.1803368801111204f  // 0.125 * log2(e), folded into Q

__device__ inline ushort f2bf(float f) {
    unsigned int i = __builtin_bit_cast(unsigned int, f);
    unsigned int r = (i + 0x7FFFu + ((i >> 16) & 1u)) >> 16;  // RNE
    return (ushort)r;
}
// hardware v_cvt_pk_bf16_f32 (memcpy dodges non-trivially-copyable bit_cast)
__device__ inline u32 pack_bf16(float a, float b) {
    float2 f2; f2.x = a; f2.y = b;
    __hip_bfloat162 h = __float22bfloat162_rn(f2);
    u32 r; __builtin_memcpy(&r, &h, 4);
    return r;
}

// async 16B global->LDS (lane i lands at wave-uniform base + i*16)
__device__ __forceinline__ void gload_lds16(const ushort* g, ushort* l) {
    __builtin_amdgcn_global_load_lds(
        (const __attribute__((address_space(1))) u32*)g,
        (__attribute__((address_space(3))) u32*)l, 16, 0, 0);
}

// -------- convert: x fp32 -> bf16, 8 elems/thread --------
__global__ __launch_bounds__(256) void convert_f32_bf16(
    const float* __restrict__ in, ushort* __restrict__ outp, int n8)
{
    int idx = blockIdx.x * 256 + threadIdx.x;
    if (idx >= n8) return;
    const float4 u0 = *(const float4*)&in[(size_t)idx * 8];
    const float4 u1 = *(const float4*)&in[(size_t)idx * 8 + 4];
    uint2v a, b;
    a.x = pack_bf16(u0.x, u0.y); a.y = pack_bf16(u0.z, u0.w);
    b.x = pack_bf16(u1.x, u1.y); b.y = pack_bf16(u1.z, u1.w);
    *(uint2v*)&outp[(size_t)idx * 8] = a;
    *(uint2v*)&outp[(size_t)idx * 8 + 4] = b;
}

// -------- transpose+convert: W[K][N] (fp32) -> Wt[N][K] (bf16) --------
__global__ __launch_bounds__(256) void transpose_f32_bf16(
    const float* __restrict__ W, ushort* __restrict__ Wt, int K, int N)
{
    __shared__ float tile[32][33];
    const int n0 = blockIdx.x * 32;
    const int k0 = blockIdx.y * 32;
    const int tx = threadIdx.x & 31;
    const int ty = threadIdx.x >> 5;
    for (int i = ty; i < 32; i += 8)
        tile[i][tx] = W[(size_t)(k0 + i) * N + n0 + tx];
    __syncthreads();
    for (int i = ty; i < 32; i += 8)
        Wt[(size_t)(n0 + i) * K + k0 + tx] = f2bf(tile[tx][i]);
}

// ------ GEMM (128x128 tile): C = A * Bt^T + bias ------
// QKV_MODE: col<768 (Q) -> *QSCALE ->C; col<1536 (K) -> C; else (V) -> Vt
template <bool OUT_FP32, bool QKV_MODE>
__global__ __launch_bounds__(256) void gemm_bt(
    const ushort* __restrict__ A, const ushort* __restrict__ Bt,
    const float* __restrict__ bias, void* __restrict__ C,
    ushort* __restrict__ Vt, int M, int N, int K, int ldc)
{
    __shared__ __attribute__((aligned(16))) ushort As[128][64];
    __shared__ __attribute__((aligned(16))) ushort Bs[128][64];
    const int tid  = threadIdx.x;
    const int lane = tid & 63;
    const int w    = tid >> 6;
    const int wm   = (w >> 1) * 64;
    const int wn   = (w & 1) * 64;
    const int g    = lane >> 4;
    const int t    = lane & 15;
    const int m0   = blockIdx.y * 128;
    const int n0   = blockIdx.x * 128;

    const int lr = lane >> 3;       // 0..7
    const int pc = lane & 7;        // 0..7

    f32x4 acc[4][4];
#pragma unroll
    for (int i = 0; i < 4; i++)
#pragma unroll
        for (int j = 0; j < 4; j++) acc[i][j] = {0.f, 0.f, 0.f, 0.f};

    const int xorc = t & 7;

    for (int k0 = 0; k0 < K; k0 += 64) {
#pragma unroll
        for (int p = 0; p < 4; p++) {
            const int row = w * 32 + p * 8 + lr;            // 0..127
            const int gc  = pc ^ (row & 7);
            gload_lds16(&A[(size_t)(m0 + row) * K + k0 + gc * 8], &As[w * 32 + p * 8][0]);
            gload_lds16(&Bt[(size_t)(n0 + row) * K + k0 + gc * 8], &Bs[w * 32 + p * 8][0]);
        }
        __syncthreads();
#pragma unroll
        for (int s = 0; s < 2; s++) {
            short8 a[4], b[4];
            const int ca = ((s * 4 + g) ^ xorc) * 8;
#pragma unroll
            for (int i = 0; i < 4; i++)
                a[i] = *(const short8*)&As[wm + i * 16 + t][ca];
#pragma unroll
            for (int j = 0; j < 4; j++)
                b[j] = *(const short8*)&Bs[wn + j * 16 + t][ca];
#pragma unroll
            for (int i = 0; i < 4; i++)
#pragma unroll
                for (int j = 0; j < 4; j++)
                    acc[i][j] = __builtin_amdgcn_mfma_f32_16x16x32_bf16(
                        a[i], b[j], acc[i][j], 0, 0, 0);
        }
        __syncthreads();
    }

#pragma unroll
    for (int j = 0; j < 4; j++) {
        int col = n0 + wn + j * 16 + t;
        float bv = bias[col];
        if (QKV_MODE && col >= 1536) {
            int h = (col - 1536) >> 6, d = col & 63;
#pragma unroll
            for (int i = 0; i < 4; i++) {
                int n = m0 + wm + i * 16 + g * 4;
                int bb = n >> 10, nn = n & 1023;
                uint2v u;
                u.x = pack_bf16(acc[i][j][0] + bv, acc[i][j][1] + bv);
                u.y = pack_bf16(acc[i][j][2] + bv, acc[i][j][3] + bv);
                *(uint2v*)&Vt[(((size_t)bb * 12 + h) * 64 + d) * 1024 + nn] = u;
            }
        } else {
#pragma unroll
            for (int i = 0; i < 4; i++)
#pragma unroll
                for (int r = 0; r < 4; r++) {
                    int row = m0 + wm + i * 16 + g * 4 + r;
                    float val = acc[i][j][r] + bv;
                    if (QKV_MODE && col < 768) val *= QSCALE;
                    if (OUT_FP32) ((float*)C)[(size_t)row * ldc + col] = val;
                    else          ((ushort*)C)[(size_t)row * ldc + col] = f2bf(val);
                }
        }
    }
}

// ------ GEMM small-N (64x128 tile, 4 waves x [64r x 32c]): balanced proj ------
__global__ __launch_bounds__(256) void gemm_bt2(
    const ushort* __restrict__ A, const ushort* __restrict__ Bt,
    const float* __restrict__ bias, float* __restrict__ C,
    int M, int N, int K, int ldc)
{
    __shared__ __attribute__((aligned(16))) ushort As[64][64];
    __shared__ __attribute__((aligned(16))) ushort Bs[128][64];
    const int tid  = threadIdx.x;
    const int lane = tid & 63;
    const int w    = tid >> 6;
    const int g    = lane >> 4;
    const int t    = lane & 15;
    const int m0   = blockIdx.y * 64;
    const int n0   = blockIdx.x * 128;
    const int wn   = w * 32;

    const int lr = lane >> 3;
    const int pc = lane & 7;

    f32x4 acc[4][2];
#pragma unroll
    for (int i = 0; i < 4; i++)
#pragma unroll
        for (int j = 0; j < 2; j++) acc[i][j] = {0.f, 0.f, 0.f, 0.f};

    const int xorc = t & 7;

    for (int k0 = 0; k0 < K; k0 += 64) {
        // A: 64 rows, wave w covers rows w*16 .. w*16+15 (2 passes of 8 rows)
#pragma unroll
        for (int p = 0; p < 2; p++) {
            const int row = w * 16 + p * 8 + lr;
            const int gc  = pc ^ (row & 7);
            gload_lds16(&A[(size_t)(m0 + row) * K + k0 + gc * 8], &As[w * 16 + p * 8][0]);
        }
        // B: 128 rows, wave w covers rows w*32 .. w*32+31 (4 passes)
#pragma unroll
        for (int p = 0; p < 4; p++) {
            const int row = w * 32 + p * 8 + lr;
            const int gc  = pc ^ (row & 7);
            gload_lds16(&Bt[(size_t)(n0 + row) * K + k0 + gc * 8], &Bs[w * 32 + p * 8][0]);
        }
        __syncthreads();
#pragma unroll
        for (int s = 0; s < 2; s++) {
            short8 a[4], b[2];
            const int ca = ((s * 4 + g) ^ xorc) * 8;
#pragma unroll
            for (int i = 0; i < 4; i++)
                a[i] = *(const short8*)&As[i * 16 + t][ca];
#pragma unroll
            for (int j = 0; j < 2; j++)
                b[j] = *(const short8*)&Bs[wn + j * 16 + t][ca];
#pragma unroll
            for (int i = 0; i < 4; i++)
#pragma unroll
                for (int j = 0; j < 2; j++)
                    acc[i][j] = __builtin_amdgcn_mfma_f32_16x16x32_bf16(
                        a[i], b[j], acc[i][j], 0, 0, 0);
        }
        __syncthreads();
    }

#pragma unroll
    for (int j = 0; j < 2; j++) {
        int col = n0 + wn + j * 16 + t;
        float bv = bias[col];
#pragma unroll
        for (int i = 0; i < 4; i++)
#pragma unroll
            for (int r = 0; r < 4; r++) {
                int row = m0 + i * 16 + g * 4 + r;
                C[(size_t)row * ldc + col] = acc[i][j][r] + bv;
            }
    }
}

// ---------------- flash attention (S^T, fixed-max, q-tile 128, single-buf) ----
// Q pre-scaled by 0.125*log2e => P = exp2f(S'). Scores bounded => fixed-max OK.
// qk (bf16): [NB,1024,1536]; Vt (bf16): [NB,12,64,1024]; out (bf16): [NB,1024,768]
// LDS 25.6 KB -> 4 blocks/CU (VGPR-capped). Register prefetch covers the
// single-buffer: read frags->regs, barrier, commit prefetch->LDS, compute, barrier.
#define PD 72
__global__ __launch_bounds__(256) void attn_kernel(
    const ushort* __restrict__ qk, const ushort* __restrict__ Vt,
    ushort* __restrict__ out)
{
    __shared__ __attribute__((aligned(16))) ushort Ks[64][64];
    __shared__ __attribute__((aligned(16))) ushort Vs[64][64];
    __shared__ __attribute__((aligned(16))) ushort Ps[4][16][PD];

    const int tid  = threadIdx.x;
    const int lane = tid & 63;
    const int w    = tid >> 6;
    const int g    = lane >> 4;
    const int t    = lane & 15;
    const int q0   = blockIdx.x * 128;
    const int h    = blockIdx.y;
    const int b    = blockIdx.z;

    const int srow = tid >> 3;       // 0..31
    const int pc   = tid & 7;        // chunk 0..7
    const size_t base  = (size_t)b * 1024 * 1536;
    const size_t vbase = ((size_t)b * 12 + h) * 64 * 1024;

    short8 qfrag[2][2];
#pragma unroll
    for (int qf = 0; qf < 2; qf++)
#pragma unroll
        for (int s = 0; s < 2; s++)
            qfrag[qf][s] = *(const short8*)&qk[base +
                (size_t)(q0 + qf * 64 + w * 16 + t) * 1536 + h * 64 + s * 32 + g * 8];

    // stage tile 0 directly (XOR chunk swizzle: phys chunk = pc ^ (row&7))
#pragma unroll
    for (int p = 0; p < 2; p++) {
        int r = srow + 32 * p;
        int c = (pc ^ (r & 7)) * 8;
        *(short8*)&Ks[r][c] =
            *(const short8*)&qk[base + (size_t)r * 1536 + 768 + h * 64 + pc * 8];
        *(short8*)&Vs[r][c] =
            *(const short8*)&Vt[vbase + (size_t)r * 1024 + pc * 8];
    }
    // prefetch tile 1 -> regs
    short8 kpre[2], vpre[2];
#pragma unroll
    for (int p = 0; p < 2; p++) {
        int r = srow + 32 * p;
        kpre[p] = *(const short8*)&qk[base + (size_t)(64 + r) * 1536 + 768 + h * 64 + pc * 8];
        vpre[p] = *(const short8*)&Vt[vbase + (size_t)r * 1024 + 64 + pc * 8];
    }
    __syncthreads();

    f32x4 o_acc[2][4];
#pragma unroll
    for (int qf = 0; qf < 2; qf++)
#pragma unroll
        for (int j = 0; j < 4; j++) o_acc[qf][j] = {0.f, 0.f, 0.f, 0.f};
    float l_part[2] = {0.f, 0.f};

    for (int kt = 0; kt < 16; kt++) {
        // K,V fragments to registers (tile kt); reused by both q-fragments
        short8 kf[2][4], bv[2][4];
#pragma unroll
        for (int s = 0; s < 2; s++)
#pragma unroll
            for (int j = 0; j < 4; j++) {
                const int row = j * 16 + t;
                const int c = ((s * 4 + g) ^ (t & 7)) * 8;
                kf[s][j] = *(const short8*)&Ks[row][c];
                bv[s][j] = *(const short8*)&Vs[row][c];
            }
        __syncthreads();  // all waves done reading tile kt from LDS

        // commit prefetched tile kt+1, then issue prefetch of kt+2
        if (kt < 15) {
#pragma unroll
            for (int p = 0; p < 2; p++) {
                int r = srow + 32 * p;
                int c = (pc ^ (r & 7)) * 8;
                *(short8*)&Ks[r][c] = kpre[p];
                *(short8*)&Vs[r][c] = vpre[p];
            }
            if (kt < 14) {
                const int kb = (kt + 2) * 64;
#pragma unroll
                for (int p = 0; p < 2; p++) {
                    int r = srow + 32 * p;
                    kpre[p] = *(const short8*)&qk[base + (size_t)(kb + r) * 1536 + 768 + h * 64 + pc * 8];
                    vpre[p] = *(const short8*)&Vt[vbase + (size_t)r * 1024 + kb + pc * 8];
                }
            }
        }

        // compute (overlaps the LDS-write settling)
#pragma unroll
        for (int qf = 0; qf < 2; qf++) {
            f32x4 s_acc[4];
#pragma unroll
            for (int j = 0; j < 4; j++) s_acc[j] = {0.f, 0.f, 0.f, 0.f};
#pragma unroll
            for (int s = 0; s < 2; s++)
#pragma unroll
                for (int j = 0; j < 4; j++)
                    s_acc[j] = __builtin_amdgcn_mfma_f32_16x16x32_bf16(
                        kf[s][j], qfrag[qf][s], s_acc[j], 0, 0, 0);

#pragma unroll
            for (int j = 0; j < 4; j++) {
                float p0 = exp2f(s_acc[j][0]);
                float p1 = exp2f(s_acc[j][1]);
                float p2 = exp2f(s_acc[j][2]);
                float p3 = exp2f(s_acc[j][3]);
                l_part[qf] += (p0 + p1) + (p2 + p3);
                uint2v u;
                u.x = pack_bf16(p0, p1);
                u.y = pack_bf16(p2, p3);
                *(uint2v*)&Ps[w][t][j * 16 + g * 4] = u;
            }

#pragma unroll
            for (int s = 0; s < 2; s++) {
                short8 a = *(const short8*)&Ps[w][t][s * 32 + g * 8];
#pragma unroll
                for (int j = 0; j < 4; j++)
                    o_acc[qf][j] = __builtin_amdgcn_mfma_f32_16x16x32_bf16(
                        a, bv[s][j], o_acc[qf][j], 0, 0, 0);
            }
        }
        __syncthreads();  // tile kt+1 writes visible before next iter's reads
    }

    // epilogue per q-fragment
#pragma unroll
    for (int qf = 0; qf < 2; qf++) {
        float l_tot = l_part[qf];
        l_tot += __shfl_xor(l_tot, 16);
        l_tot += __shfl_xor(l_tot, 32);
        float il[4];
#pragma unroll
        for (int r = 0; r < 4; r++) il[r] = 1.0f / __shfl(l_tot, g * 4 + r);
#pragma unroll
        for (int r = 0; r < 4; r++) {
            int row = q0 + qf * 64 + w * 16 + g * 4 + r;
#pragma unroll
            for (int j = 0; j < 4; j++)
                out[((size_t)(b * 1024 + row)) * 768 + h * 64 + j * 16 + t] =
                    f2bf(o_acc[qf][j][r] * il[r]);
        }
    }
}

extern "C" void kernel_launch(void* const* d_in, const int* in_sizes, int n_in,
                              void* d_out, int out_size, void* d_ws, size_t ws_size,
                              hipStream_t stream)
{
    const float* x      = (const float*)d_in[0];  // [8,1024,768] fp32
    const float* qkv_w  = (const float*)d_in[1];  // [768,2304]   fp32
    const float* qkv_b  = (const float*)d_in[2];  // [2304]       fp32
    const float* proj_w = (const float*)d_in[3];  // [768,768]    fp32
    const float* proj_b = (const float*)d_in[4];  // [768]        fp32
    float* out = (float*)d_out;                   // [8,1024,768] fp32

    char* ws = (char*)d_ws;
    ushort* Wt1 = (ushort*)ws;                               // 2304*768 bf16
    ushort* Wt2 = Wt1 + (size_t)2304 * 768;                  // 768*768  bf16
    char*   buf = (char*)(Wt2 + (size_t)768 * 768);

    transpose_f32_bf16<<<dim3(72, 24), 256, 0, stream>>>(qkv_w, Wt1, 768, 2304);
    transpose_f32_bf16<<<dim3(24, 24), 256, 0, stream>>>(proj_w, Wt2, 768, 768);

    const size_t wt_bytes   = ((size_t)2304 * 768 + (size_t)768 * 768) * 2;
    const size_t full_bytes = wt_bytes + (size_t)8192 * 768 * 2    // xb
                                       + (size_t)8192 * 1536 * 2   // qk
                                       + (size_t)8192 * 768 * 2    // Vt
                                       + (size_t)8192 * 768 * 2;   // attnO

    if (ws_size >= full_bytes) {
        ushort* xb    = (ushort*)buf;
        ushort* qkO   = xb + (size_t)8192 * 768;
        ushort* VtO   = qkO + (size_t)8192 * 1536;
        ushort* attnO = VtO + (size_t)8192 * 768;
        convert_f32_bf16<<<dim3(3072), 256, 0, stream>>>(x, xb, 786432);
        gemm_bt<false, true><<<dim3(18, 64), 256, 0, stream>>>(
            xb, Wt1, qkv_b, qkO, VtO, 8192, 2304, 768, 1536);
        attn_kernel<<<dim3(8, 12, 8), 256, 0, stream>>>(qkO, VtO, attnO);
        gemm_bt2<<<dim3(6, 128), 256, 0, stream>>>(
            attnO, Wt2, proj_b, out, 8192, 768, 768, 768);
    } else {
        // Per-batch path: ~13 MB workspace.
        ushort* xbB   = (ushort*)buf;
        ushort* qkB   = xbB + (size_t)1024 * 768;
        ushort* VtB   = qkB + (size_t)1024 * 1536;
        ushort* attnB = VtB + (size_t)1024 * 768;
        for (int b = 0; b < 8; b++) {
            const float* xp = x + (size_t)b * 1024 * 768;
            float* outb = out + (size_t)b * 1024 * 768;
            convert_f32_bf16<<<dim3(384), 256, 0, stream>>>(xp, xbB, 98304);
            gemm_bt<false, true><<<dim3(18, 8), 256, 0, stream>>>(
                xbB, Wt1, qkv_b, qkB, VtB, 1024, 2304, 768, 1536);
            attn_kernel<<<dim3(8, 12, 1), 256, 0, stream>>>(qkB, VtB, attnB);
            gemm_bt2<<<dim3(6, 16), 256, 0, stream>>>(
                attnB, Wt2, proj_b, outb, 1024, 768, 768, 768);
        }
    }
}

// Round 11
// 196.852 us; speedup vs baseline: 1.0623x; 1.0623x over previous
//
#include <hip/hip_runtime.h>
#include <hip/hip_bf16.h>

typedef __attribute__((ext_vector_type(8))) short short8;
typedef __attribute__((ext_vector_type(4))) float f32x4;
typedef __attribute__((ext_vector_type(2))) unsigned int uint2v;
typedef unsigned int u32;

#define QSCALE 0.1803368801111204f  // 0.125 * log2(e), folded into Q

__device__ inline ushort f2bf(float f) {
    unsigned int i = __builtin_bit_cast(unsigned int, f);
    unsigned int r = (i + 0x7FFFu + ((i >> 16) & 1u)) >> 16;  // RNE
    return (ushort)r;
}
// hardware v_cvt_pk_bf16_f32 (memcpy dodges non-trivially-copyable bit_cast)
__device__ inline u32 pack_bf16(float a, float b) {
    float2 f2; f2.x = a; f2.y = b;
    __hip_bfloat162 h = __float22bfloat162_rn(f2);
    u32 r; __builtin_memcpy(&r, &h, 4);
    return r;
}

// async 16B global->LDS (lane i lands at wave-uniform base + i*16)
__device__ __forceinline__ void gload_lds16(const ushort* g, ushort* l) {
    __builtin_amdgcn_global_load_lds(
        (const __attribute__((address_space(1))) u32*)g,
        (__attribute__((address_space(3))) u32*)l, 16, 0, 0);
}

// -------- convert: x fp32 -> bf16, 8 elems/thread --------
__global__ __launch_bounds__(256) void convert_f32_bf16(
    const float* __restrict__ in, ushort* __restrict__ outp, int n8)
{
    int idx = blockIdx.x * 256 + threadIdx.x;
    if (idx >= n8) return;
    const float4 u0 = *(const float4*)&in[(size_t)idx * 8];
    const float4 u1 = *(const float4*)&in[(size_t)idx * 8 + 4];
    uint2v a, b;
    a.x = pack_bf16(u0.x, u0.y); a.y = pack_bf16(u0.z, u0.w);
    b.x = pack_bf16(u1.x, u1.y); b.y = pack_bf16(u1.z, u1.w);
    *(uint2v*)&outp[(size_t)idx * 8] = a;
    *(uint2v*)&outp[(size_t)idx * 8 + 4] = b;
}

// -------- transpose+convert: W[K][N] (fp32) -> Wt[N][K] (bf16) --------
__global__ __launch_bounds__(256) void transpose_f32_bf16(
    const float* __restrict__ W, ushort* __restrict__ Wt, int K, int N)
{
    __shared__ float tile[32][33];
    const int n0 = blockIdx.x * 32;
    const int k0 = blockIdx.y * 32;
    const int tx = threadIdx.x & 31;
    const int ty = threadIdx.x >> 5;
    for (int i = ty; i < 32; i += 8)
        tile[i][tx] = W[(size_t)(k0 + i) * N + n0 + tx];
    __syncthreads();
    for (int i = ty; i < 32; i += 8)
        Wt[(size_t)(n0 + i) * K + k0 + tx] = f2bf(tile[tx][i]);
}

// ------ GEMM (128x128 tile): C = A * Bt^T + bias ------
// grid: x = m-tile (multiple of 8 -> same-XCD A reuse), y = n-tile.
// QKV_MODE: col<768 (Q) -> *QSCALE ->C; col<1536 (K) -> C; else (V) -> Vt
template <bool OUT_FP32, bool QKV_MODE>
__global__ __launch_bounds__(256) void gemm_bt(
    const ushort* __restrict__ A, const ushort* __restrict__ Bt,
    const float* __restrict__ bias, void* __restrict__ C,
    ushort* __restrict__ Vt, int M, int N, int K, int ldc)
{
    __shared__ __attribute__((aligned(16))) ushort As[128][64];
    __shared__ __attribute__((aligned(16))) ushort Bs[128][64];
    const int tid  = threadIdx.x;
    const int lane = tid & 63;
    const int w    = tid >> 6;
    const int wm   = (w >> 1) * 64;
    const int wn   = (w & 1) * 64;
    const int g    = lane >> 4;
    const int t    = lane & 15;
    const int m0   = blockIdx.x * 128;
    const int n0   = blockIdx.y * 128;

    const int lr = lane >> 3;       // 0..7
    const int pc = lane & 7;        // 0..7

    f32x4 acc[4][4];
#pragma unroll
    for (int i = 0; i < 4; i++)
#pragma unroll
        for (int j = 0; j < 4; j++) acc[i][j] = {0.f, 0.f, 0.f, 0.f};

    const int xorc = t & 7;

    for (int k0 = 0; k0 < K; k0 += 64) {
#pragma unroll
        for (int p = 0; p < 4; p++) {
            const int row = w * 32 + p * 8 + lr;            // 0..127
            const int gc  = pc ^ (row & 7);
            gload_lds16(&A[(size_t)(m0 + row) * K + k0 + gc * 8], &As[w * 32 + p * 8][0]);
            gload_lds16(&Bt[(size_t)(n0 + row) * K + k0 + gc * 8], &Bs[w * 32 + p * 8][0]);
        }
        __syncthreads();
#pragma unroll
        for (int s = 0; s < 2; s++) {
            short8 a[4], b[4];
            const int ca = ((s * 4 + g) ^ xorc) * 8;
#pragma unroll
            for (int i = 0; i < 4; i++)
                a[i] = *(const short8*)&As[wm + i * 16 + t][ca];
#pragma unroll
            for (int j = 0; j < 4; j++)
                b[j] = *(const short8*)&Bs[wn + j * 16 + t][ca];
#pragma unroll
            for (int i = 0; i < 4; i++)
#pragma unroll
                for (int j = 0; j < 4; j++)
                    acc[i][j] = __builtin_amdgcn_mfma_f32_16x16x32_bf16(
                        a[i], b[j], acc[i][j], 0, 0, 0);
        }
        __syncthreads();
    }

#pragma unroll
    for (int j = 0; j < 4; j++) {
        int col = n0 + wn + j * 16 + t;
        float bv = bias[col];
        if (QKV_MODE && col >= 1536) {
            int h = (col - 1536) >> 6, d = col & 63;
#pragma unroll
            for (int i = 0; i < 4; i++) {
                int n = m0 + wm + i * 16 + g * 4;
                int bb = n >> 10, nn = n & 1023;
                uint2v u;
                u.x = pack_bf16(acc[i][j][0] + bv, acc[i][j][1] + bv);
                u.y = pack_bf16(acc[i][j][2] + bv, acc[i][j][3] + bv);
                *(uint2v*)&Vt[(((size_t)bb * 12 + h) * 64 + d) * 1024 + nn] = u;
            }
        } else {
#pragma unroll
            for (int i = 0; i < 4; i++)
#pragma unroll
                for (int r = 0; r < 4; r++) {
                    int row = m0 + wm + i * 16 + g * 4 + r;
                    float val = acc[i][j][r] + bv;
                    if (QKV_MODE && col < 768) val *= QSCALE;
                    if (OUT_FP32) ((float*)C)[(size_t)row * ldc + col] = val;
                    else          ((ushort*)C)[(size_t)row * ldc + col] = f2bf(val);
                }
        }
    }
}

// ------ GEMM small-N (64x128 tile): balanced proj; grid x = m-tile ------
__global__ __launch_bounds__(256) void gemm_bt2(
    const ushort* __restrict__ A, const ushort* __restrict__ Bt,
    const float* __restrict__ bias, float* __restrict__ C,
    int M, int N, int K, int ldc)
{
    __shared__ __attribute__((aligned(16))) ushort As[64][64];
    __shared__ __attribute__((aligned(16))) ushort Bs[128][64];
    const int tid  = threadIdx.x;
    const int lane = tid & 63;
    const int w    = tid >> 6;
    const int g    = lane >> 4;
    const int t    = lane & 15;
    const int m0   = blockIdx.x * 64;
    const int n0   = blockIdx.y * 128;
    const int wn   = w * 32;

    const int lr = lane >> 3;
    const int pc = lane & 7;

    f32x4 acc[4][2];
#pragma unroll
    for (int i = 0; i < 4; i++)
#pragma unroll
        for (int j = 0; j < 2; j++) acc[i][j] = {0.f, 0.f, 0.f, 0.f};

    const int xorc = t & 7;

    for (int k0 = 0; k0 < K; k0 += 64) {
#pragma unroll
        for (int p = 0; p < 2; p++) {
            const int row = w * 16 + p * 8 + lr;
            const int gc  = pc ^ (row & 7);
            gload_lds16(&A[(size_t)(m0 + row) * K + k0 + gc * 8], &As[w * 16 + p * 8][0]);
        }
#pragma unroll
        for (int p = 0; p < 4; p++) {
            const int row = w * 32 + p * 8 + lr;
            const int gc  = pc ^ (row & 7);
            gload_lds16(&Bt[(size_t)(n0 + row) * K + k0 + gc * 8], &Bs[w * 32 + p * 8][0]);
        }
        __syncthreads();
#pragma unroll
        for (int s = 0; s < 2; s++) {
            short8 a[4], b[2];
            const int ca = ((s * 4 + g) ^ xorc) * 8;
#pragma unroll
            for (int i = 0; i < 4; i++)
                a[i] = *(const short8*)&As[i * 16 + t][ca];
#pragma unroll
            for (int j = 0; j < 2; j++)
                b[j] = *(const short8*)&Bs[wn + j * 16 + t][ca];
#pragma unroll
            for (int i = 0; i < 4; i++)
#pragma unroll
                for (int j = 0; j < 2; j++)
                    acc[i][j] = __builtin_amdgcn_mfma_f32_16x16x32_bf16(
                        a[i], b[j], acc[i][j], 0, 0, 0);
        }
        __syncthreads();
    }

#pragma unroll
    for (int j = 0; j < 2; j++) {
        int col = n0 + wn + j * 16 + t;
        float bv = bias[col];
#pragma unroll
        for (int i = 0; i < 4; i++)
#pragma unroll
            for (int r = 0; r < 4; r++) {
                int row = m0 + i * 16 + g * 4 + r;
                C[(size_t)row * ldc + col] = acc[i][j][r] + bv;
            }
    }
}

// ---------------- flash attention (S^T, fixed-max, q-tile 128, dbuf) ----------
// grid: x = b*12+h (96), y = q-tile (8). q-tiles of one (b,h) are 96 apart
// in dispatch order, 96 % 8 == 0 -> same XCD -> K/V served from that XCD's L2.
// Q pre-scaled by 0.125*log2e => P = exp2f(S'). Scores bounded => fixed-max OK.
#define PD 72
__global__ __launch_bounds__(256) void attn_kernel(
    const ushort* __restrict__ qk, const ushort* __restrict__ Vt,
    ushort* __restrict__ out)
{
    __shared__ __attribute__((aligned(16))) ushort Ks[2][64][64];
    __shared__ __attribute__((aligned(16))) ushort Vs[2][64][64];
    __shared__ __attribute__((aligned(16))) ushort Ps[4][16][PD];

    const int tid  = threadIdx.x;
    const int lane = tid & 63;
    const int w    = tid >> 6;
    const int g    = lane >> 4;
    const int t    = lane & 15;
    const int bh   = blockIdx.x;
    const int b    = bh / 12;
    const int h    = bh - b * 12;
    const int q0   = blockIdx.y * 128;

    const int srow = tid >> 3;       // 0..31
    const int pc   = tid & 7;        // chunk 0..7
    const size_t base  = (size_t)b * 1024 * 1536;
    const size_t vbase = ((size_t)b * 12 + h) * 64 * 1024;

    short8 qfrag[2][2];
#pragma unroll
    for (int qf = 0; qf < 2; qf++)
#pragma unroll
        for (int s = 0; s < 2; s++)
            qfrag[qf][s] = *(const short8*)&qk[base +
                (size_t)(q0 + qf * 64 + w * 16 + t) * 1536 + h * 64 + s * 32 + g * 8];

    // stage tile 0 (XOR chunk swizzle: phys chunk = pc ^ (row&7))
#pragma unroll
    for (int p = 0; p < 2; p++) {
        int r = srow + 32 * p;
        int c = (pc ^ (r & 7)) * 8;
        *(short8*)&Ks[0][r][c] =
            *(const short8*)&qk[base + (size_t)r * 1536 + 768 + h * 64 + pc * 8];
        *(short8*)&Vs[0][r][c] =
            *(const short8*)&Vt[vbase + (size_t)r * 1024 + pc * 8];
    }
    __syncthreads();

    f32x4 o_acc[2][4];
#pragma unroll
    for (int qf = 0; qf < 2; qf++)
#pragma unroll
        for (int j = 0; j < 4; j++) o_acc[qf][j] = {0.f, 0.f, 0.f, 0.f};
    float l_part[2] = {0.f, 0.f};

    for (int kt = 0; kt < 16; kt++) {
        const int cur = kt & 1;

        short8 kpre[2], vpre[2];
        if (kt < 15) {
            const int kb = (kt + 1) * 64;
#pragma unroll
            for (int p = 0; p < 2; p++) {
                int r = srow + 32 * p;
                kpre[p] = *(const short8*)&qk[base + (size_t)(kb + r) * 1536 + 768 + h * 64 + pc * 8];
                vpre[p] = *(const short8*)&Vt[vbase + (size_t)r * 1024 + kb + pc * 8];
            }
        }

        // K,V fragments to registers once; reused by both q-fragments
        short8 kf[2][4], bv[2][4];
#pragma unroll
        for (int s = 0; s < 2; s++)
#pragma unroll
            for (int j = 0; j < 4; j++) {
                const int row = j * 16 + t;
                const int c = ((s * 4 + g) ^ (t & 7)) * 8;
                kf[s][j] = *(const short8*)&Ks[cur][row][c];
                bv[s][j] = *(const short8*)&Vs[cur][row][c];
            }

#pragma unroll
        for (int qf = 0; qf < 2; qf++) {
            f32x4 s_acc[4];
#pragma unroll
            for (int j = 0; j < 4; j++) s_acc[j] = {0.f, 0.f, 0.f, 0.f};
#pragma unroll
            for (int s = 0; s < 2; s++)
#pragma unroll
                for (int j = 0; j < 4; j++)
                    s_acc[j] = __builtin_amdgcn_mfma_f32_16x16x32_bf16(
                        kf[s][j], qfrag[qf][s], s_acc[j], 0, 0, 0);

#pragma unroll
            for (int j = 0; j < 4; j++) {
                float p0 = exp2f(s_acc[j][0]);
                float p1 = exp2f(s_acc[j][1]);
                float p2 = exp2f(s_acc[j][2]);
                float p3 = exp2f(s_acc[j][3]);
                l_part[qf] += (p0 + p1) + (p2 + p3);
                uint2v u;
                u.x = pack_bf16(p0, p1);
                u.y = pack_bf16(p2, p3);
                *(uint2v*)&Ps[w][t][j * 16 + g * 4] = u;
            }

#pragma unroll
            for (int s = 0; s < 2; s++) {
                short8 a = *(const short8*)&Ps[w][t][s * 32 + g * 8];
#pragma unroll
                for (int j = 0; j < 4; j++)
                    o_acc[qf][j] = __builtin_amdgcn_mfma_f32_16x16x32_bf16(
                        a, bv[s][j], o_acc[qf][j], 0, 0, 0);
            }
        }

        if (kt < 15) {
#pragma unroll
            for (int p = 0; p < 2; p++) {
                int r = srow + 32 * p;
                int c = (pc ^ (r & 7)) * 8;
                *(short8*)&Ks[cur ^ 1][r][c] = kpre[p];
                *(short8*)&Vs[cur ^ 1][r][c] = vpre[p];
            }
        }
        __syncthreads();
    }

    // epilogue per q-fragment
#pragma unroll
    for (int qf = 0; qf < 2; qf++) {
        float l_tot = l_part[qf];
        l_tot += __shfl_xor(l_tot, 16);
        l_tot += __shfl_xor(l_tot, 32);
        float il[4];
#pragma unroll
        for (int r = 0; r < 4; r++) il[r] = 1.0f / __shfl(l_tot, g * 4 + r);
#pragma unroll
        for (int r = 0; r < 4; r++) {
            int row = q0 + qf * 64 + w * 16 + g * 4 + r;
#pragma unroll
            for (int j = 0; j < 4; j++)
                out[((size_t)(b * 1024 + row)) * 768 + h * 64 + j * 16 + t] =
                    f2bf(o_acc[qf][j][r] * il[r]);
        }
    }
}

extern "C" void kernel_launch(void* const* d_in, const int* in_sizes, int n_in,
                              void* d_out, int out_size, void* d_ws, size_t ws_size,
                              hipStream_t stream)
{
    const float* x      = (const float*)d_in[0];  // [8,1024,768] fp32
    const float* qkv_w  = (const float*)d_in[1];  // [768,2304]   fp32
    const float* qkv_b  = (const float*)d_in[2];  // [2304]       fp32
    const float* proj_w = (const float*)d_in[3];  // [768,768]    fp32
    const float* proj_b = (const float*)d_in[4];  // [768]        fp32
    float* out = (float*)d_out;                   // [8,1024,768] fp32

    char* ws = (char*)d_ws;
    ushort* Wt1 = (ushort*)ws;                               // 2304*768 bf16
    ushort* Wt2 = Wt1 + (size_t)2304 * 768;                  // 768*768  bf16
    char*   buf = (char*)(Wt2 + (size_t)768 * 768);

    transpose_f32_bf16<<<dim3(72, 24), 256, 0, stream>>>(qkv_w, Wt1, 768, 2304);
    transpose_f32_bf16<<<dim3(24, 24), 256, 0, stream>>>(proj_w, Wt2, 768, 768);

    const size_t wt_bytes   = ((size_t)2304 * 768 + (size_t)768 * 768) * 2;
    const size_t full_bytes = wt_bytes + (size_t)8192 * 768 * 2    // xb
                                       + (size_t)8192 * 1536 * 2   // qk
                                       + (size_t)8192 * 768 * 2    // Vt
                                       + (size_t)8192 * 768 * 2;   // attnO

    if (ws_size >= full_bytes) {
        ushort* xb    = (ushort*)buf;
        ushort* qkO   = xb + (size_t)8192 * 768;
        ushort* VtO   = qkO + (size_t)8192 * 1536;
        ushort* attnO = VtO + (size_t)8192 * 768;
        convert_f32_bf16<<<dim3(3072), 256, 0, stream>>>(x, xb, 786432);
        gemm_bt<false, true><<<dim3(64, 18), 256, 0, stream>>>(
            xb, Wt1, qkv_b, qkO, VtO, 8192, 2304, 768, 1536);
        attn_kernel<<<dim3(96, 8), 256, 0, stream>>>(qkO, VtO, attnO);
        gemm_bt2<<<dim3(128, 6), 256, 0, stream>>>(
            attnO, Wt2, proj_b, out, 8192, 768, 768, 768);
    } else {
        // Per-batch path: ~13 MB workspace.
        ushort* xbB   = (ushort*)buf;
        ushort* qkB   = xbB + (size_t)1024 * 768;
        ushort* VtB   = qkB + (size_t)1024 * 1536;
        ushort* attnB = VtB + (size_t)1024 * 768;
        for (int b = 0; b < 8; b++) {
            const float* xp = x + (size_t)b * 1024 * 768;
            float* outb = out + (size_t)b * 1024 * 768;
            convert_f32_bf16<<<dim3(384), 256, 0, stream>>>(xp, xbB, 98304);
            gemm_bt<false, true><<<dim3(8, 18), 256, 0, stream>>>(
                xbB, Wt1, qkv_b, qkB, VtB, 1024, 2304, 768, 1536);
            attn_kernel<<<dim3(12, 8), 256, 0, stream>>>(qkB, VtB, attnB);
            gemm_bt2<<<dim3(16, 6), 256, 0, stream>>>(
                attnB, Wt2, proj_b, outb, 1024, 768, 768, 768);
        }
    }
}